// Round 2
// baseline (291.667 us; speedup 1.0000x reference)
//
#include <hip/hip_runtime.h>
#include <stdint.h>

#define DEV __device__ __forceinline__

typedef __attribute__((ext_vector_type(8))) short bf16x8;
typedef __attribute__((ext_vector_type(4))) float f32x4;

DEV unsigned short f2bf(float f) {
  union { float f; uint32_t u; } v; v.f = f;
  uint32_t r = v.u + 0x7fffu + ((v.u >> 16) & 1u);
  return (unsigned short)(r >> 16);
}

DEV void lds_load16(void* dst, const void* src) {
  __builtin_amdgcn_global_load_lds(
      (const __attribute__((address_space(1))) unsigned int*)src,
      (__attribute__((address_space(3))) unsigned int*)dst, 16, 0, 0);
}

// ---------------- prep kernels ----------------

__global__ void conv_x_k(const float* __restrict__ x, unsigned short* __restrict__ o) {
  const int i = blockIdx.x * 256 + threadIdx.x;  // 1572864 float4s
  const float4 v = ((const float4*)x)[i];
  ushort4 u;
  u.x = f2bf(v.x); u.y = f2bf(v.y); u.z = f2bf(v.z); u.w = f2bf(v.w);
  ((ushort4*)o)[i] = u;
}

// E arrives as int32 (harness converts all integer inputs to int). 8 elems/thread.
__global__ void conv_E_k(const int* __restrict__ E, uint8_t* __restrict__ o) {
  const int i = blockIdx.x * 256 + threadIdx.x;  // 1048576 threads
  const uint4* p = (const uint4*)(E + (size_t)i * 8);
  const uint4 a = p[0], b2 = p[1];
  uint2 w;
  w.x = (a.x & 0xffu) | ((a.y & 0xffu) << 8) | ((a.z & 0xffu) << 16) | ((a.w & 0xffu) << 24);
  w.y = (b2.x & 0xffu) | ((b2.y & 0xffu) << 8) | ((b2.z & 0xffu) << 16) | ((b2.w & 0xffu) << 24);
  ((uint2*)o)[i] = w;
}

// Wt[c][k] = W[k][c], bf16 pack. grid (12,12,4): z selects Wq/Wk/Wv -> wtqkv, Wo -> wot
__global__ void transp_w_k(const float* __restrict__ Wq, const float* __restrict__ Wk,
                           const float* __restrict__ Wv, const float* __restrict__ Wo,
                           unsigned short* __restrict__ wtqkv, unsigned short* __restrict__ wot) {
  __shared__ float tile[64][65];
  const int z = blockIdx.z;
  const float* W = (z == 0) ? Wq : (z == 1) ? Wk : (z == 2) ? Wv : Wo;
  unsigned short* D = (z < 3) ? wtqkv + (size_t)z * 768 * 768 : wot;
  const int k0 = blockIdx.x * 64;
  const int c0 = blockIdx.y * 64;
  const int t = threadIdx.x;
#pragma unroll
  for (int i = 0; i < 4; ++i) {
    const int idx = i * 256 + t;
    const int r = idx >> 4;
    const int cq = (idx & 15) * 4;
    const float4 v = *(const float4*)&W[(k0 + r) * 768 + c0 + cq];
    tile[r][cq] = v.x; tile[r][cq + 1] = v.y; tile[r][cq + 2] = v.z; tile[r][cq + 3] = v.w;
  }
  __syncthreads();
#pragma unroll
  for (int i = 0; i < 4; ++i) {
    const int idx = i * 256 + t;
    const int c = idx >> 4;
    const int kq = (idx & 15) * 4;
    ushort4 u;
    u.x = f2bf(tile[kq][c]);     u.y = f2bf(tile[kq + 1][c]);
    u.z = f2bf(tile[kq + 2][c]); u.w = f2bf(tile[kq + 3][c]);
    *(ushort4*)&D[(c0 + c) * 768 + k0 + kq] = u;
  }
}

// ---------------- GEMM: C = A(M,768) @ Bt^T + bias ----------------
// A bf16 row-major (M,768); Bt bf16 (Ncols,768) (i.e. W^T, k-contiguous).
// MODE 0: Ncols=2304 (Q|K|V) -> scatter to Qb,Kb (B,h,N,d) and Vt (B,h,d,N), bf16.
// MODE 1: Ncols=768 -> Fo f32 (M,768) + bias.
template <int MODE>
__global__ __launch_bounds__(256, 2)
void gemm_bt(const unsigned short* __restrict__ A, const unsigned short* __restrict__ Bt,
             const float* __restrict__ b0, const float* __restrict__ b1, const float* __restrict__ b2,
             unsigned short* __restrict__ Qb, unsigned short* __restrict__ Kb,
             unsigned short* __restrict__ Vt, float* __restrict__ Fo) {
  __shared__ __attribute__((aligned(16))) unsigned short lds[2][8192];  // [buf][A 4096 | B 4096]
  const int t = threadIdx.x;
  const int lane = t & 63;
  const int wid = t >> 6;
  const int m0 = blockIdx.x * 128;
  const int n0 = blockIdx.y * 128;
  const int wm = (wid >> 1) * 64;
  const int wn = (wid & 1) * 64;
  const int srow = t & 127;
  const int sk8 = (t >> 7) * 8;

  const unsigned short* gA = A + (m0 + srow) * 768 + sk8;
  const unsigned short* gB = Bt + (n0 + srow) * 768 + sk8;

  const f32x4 Z4 = {0.f, 0.f, 0.f, 0.f};
  f32x4 acc[4][4];
#pragma unroll
  for (int m = 0; m < 4; ++m)
#pragma unroll
    for (int n = 0; n < 4; ++n) acc[m][n] = Z4;

  const int a_off = (lane >> 4) * 1024 + (wm + (lane & 15)) * 8;
  const int b_off = 4096 + (lane >> 4) * 1024 + (wn + (lane & 15)) * 8;

  auto stage = [&](int buf, int kt) {
    unsigned short* dA = &lds[buf][0] + wid * 512;
    unsigned short* dB = &lds[buf][4096] + wid * 512;
    const unsigned short* sA = gA + kt * 32;
    const unsigned short* sB = gB + kt * 32;
    lds_load16(dA, sA);
    lds_load16(dA + 2048, sA + 16);
    lds_load16(dB, sB);
    lds_load16(dB + 2048, sB + 16);
  };

  stage(0, 0);
  int cur = 0;
  for (int kt = 0; kt < 24; ++kt) {
    __syncthreads();
    if (kt + 1 < 24) stage(cur ^ 1, kt + 1);
    bf16x8 av[4], bvv[4];
#pragma unroll
    for (int m = 0; m < 4; ++m) av[m] = *(const bf16x8*)&lds[cur][a_off + m * 128];
#pragma unroll
    for (int n = 0; n < 4; ++n) bvv[n] = *(const bf16x8*)&lds[cur][b_off + n * 128];
#pragma unroll
    for (int m = 0; m < 4; ++m)
#pragma unroll
      for (int n = 0; n < 4; ++n)
        acc[m][n] = __builtin_amdgcn_mfma_f32_16x16x32_bf16(av[m], bvv[n], acc[m][n], 0, 0, 0);
    cur ^= 1;
  }

  const int g = lane >> 4;
  const int c15 = lane & 15;
  if (MODE == 1) {
#pragma unroll
    for (int n = 0; n < 4; ++n) {
      const int col = n0 + wn + n * 16 + c15;
      const float bval = b0[col];
#pragma unroll
      for (int m = 0; m < 4; ++m) {
        const int r0 = m0 + wm + m * 16 + g * 4;
#pragma unroll
        for (int r = 0; r < 4; ++r) Fo[(r0 + r) * 768 + col] = acc[m][n][r] + bval;
      }
    }
  } else {
    const int mat = blockIdx.y / 6;
    const float* bsel = (mat == 0) ? b0 : (mat == 1) ? b1 : b2;
    unsigned short* qk = (mat == 0) ? Qb : Kb;
#pragma unroll
    for (int n = 0; n < 4; ++n) {
      const int cw = (blockIdx.y % 6) * 128 + wn + n * 16 + c15;  // col within matrix
      const int hh = cw >> 6, dd = cw & 63;
      const float bval = bsel[cw];
#pragma unroll
      for (int m = 0; m < 4; ++m) {
        const int r0 = m0 + wm + m * 16 + g * 4;
        const int bb = r0 >> 10;
        const int nn = r0 & 1023;
        if (mat < 2) {
          unsigned short* dst = qk + ((bb * 12 + hh) * 1024 + nn) * 64 + dd;
#pragma unroll
          for (int r = 0; r < 4; ++r) dst[r * 64] = f2bf(acc[m][n][r] + bval);
        } else {
          ushort4 w;
          w.x = f2bf(acc[m][n][0] + bval);
          w.y = f2bf(acc[m][n][1] + bval);
          w.z = f2bf(acc[m][n][2] + bval);
          w.w = f2bf(acc[m][n][3] + bval);
          *(ushort4*)&Vt[((bb * 12 + hh) * 64 + dd) * 1024 + nn] = w;
        }
      }
    }
  }
}

// ---------------- fused edge-bias flash attention ----------------
// grid (16,12,8): (q-tile, head, batch). 4 waves, each owns 16 q-rows.
__global__ __launch_bounds__(256, 2)
void attn_fused(const unsigned short* __restrict__ Qb, const unsigned short* __restrict__ Kb,
                const unsigned short* __restrict__ Vt, const uint8_t* __restrict__ E8,
                const int* __restrict__ Mm, const float* __restrict__ emb,
                unsigned short* __restrict__ AO) {
  __shared__ __attribute__((aligned(16))) unsigned short Qs[4096];     // [dslot8][qrow64][8]
  __shared__ __attribute__((aligned(16))) unsigned short Ks[2][4096];  // [dslot8][kpos64][8]
  __shared__ __attribute__((aligned(16))) unsigned short Vs[2][4096];  // [kslot8][d64][8]
  __shared__ __attribute__((aligned(16))) uint8_t Es[2][4096];         // [qrow64][kpos64]
  __shared__ __attribute__((aligned(16))) unsigned short Ps[4][1024];  // per-wave P 16x64, XOR-swz
  __shared__ float biasl[32];
  __shared__ float red[4][16];

  const int t = threadIdx.x;
  const int lane = t & 63;
  const int wid = t >> 6;
  const int g = lane >> 4;
  const int c15 = lane & 15;
  const int b = blockIdx.z;
  const int h = blockIdx.y;
  const int q0 = blockIdx.x * 64;
  const int bh = b * 12 + h;

  {  // stage Q once
    const unsigned short* g0 = Qb + (bh * 1024 + q0 + (t & 63)) * 64 + wid * 8;
    unsigned short* d0 = Qs + wid * 512;
    lds_load16(d0, g0);
    lds_load16(d0 + 2048, g0 + 32);
  }
  if (t < 32) biasl[t] = emb[t * 12 + h];

  int qvr[4];
#pragma unroll
  for (int r = 0; r < 4; ++r) qvr[r] = Mm[b * 1024 + q0 + wid * 16 + g * 4 + r];

  auto stageKVE = [&](int buf, int kt) {
    const unsigned short* kg = Kb + (bh * 1024 + kt * 64 + (t & 63)) * 64 + wid * 8;
    unsigned short* kd = Ks[buf] + wid * 512;
    lds_load16(kd, kg);
    lds_load16(kd + 2048, kg + 32);
    const unsigned short* vg = Vt + (bh * 64 + (t & 63)) * 1024 + kt * 64 + wid * 8;
    unsigned short* vd = Vs[buf] + wid * 512;
    lds_load16(vd, vg);
    lds_load16(vd + 2048, vg + 32);
    const uint8_t* eg = E8 + (b * 1024 + q0 + (t >> 2)) * 1024 + kt * 64 + (t & 3) * 16;
    lds_load16(Es[buf] + wid * 1024, eg);
  };

  stageKVE(0, 0);

  float mr[4], lr2[4];
#pragma unroll
  for (int r = 0; r < 4; ++r) { mr[r] = -1e30f; lr2[r] = 0.f; }
  const f32x4 Z4 = {0.f, 0.f, 0.f, 0.f};
  f32x4 oacc[4];
#pragma unroll
  for (int mb = 0; mb < 4; ++mb) oacc[mb] = Z4;

  int cur = 0;
  const int qrow_off = (wid * 16 + c15) * 8;

  for (int kt = 0; kt < 16; ++kt) {
    __syncthreads();
    if (kt + 1 < 16) stageKVE(cur ^ 1, kt + 1);

    // S = Q K^T   (S[row=g*4+r][col=n*16+c15], rows are this wave's 16 q-rows)
    f32x4 s[4];
#pragma unroll
    for (int n = 0; n < 4; ++n) s[n] = Z4;
#pragma unroll
    for (int ks = 0; ks < 2; ++ks) {
      const bf16x8 aq = *(const bf16x8*)&Qs[(ks * 4 + g) * 512 + qrow_off];
#pragma unroll
      for (int n = 0; n < 4; ++n) {
        const bf16x8 bk2 = *(const bf16x8*)&Ks[cur][(ks * 4 + g) * 512 + (n * 16 + c15) * 8];
        s[n] = __builtin_amdgcn_mfma_f32_16x16x32_bf16(aq, bk2, s[n], 0, 0, 0);
      }
    }

    // scale + edge bias + dual mask
    int kvn[4];
#pragma unroll
    for (int n = 0; n < 4; ++n) kvn[n] = Mm[b * 1024 + kt * 64 + n * 16 + c15];
#pragma unroll
    for (int n = 0; n < 4; ++n) {
#pragma unroll
      for (int r = 0; r < 4; ++r) {
        const int e = Es[cur][(wid * 16 + g * 4 + r) * 64 + n * 16 + c15];
        const float sv = s[n][r] * 0.125f + biasl[e];
        s[n][r] = (qvr[r] != 0 && kvn[n] != 0) ? sv : -1e9f;
      }
    }

    // row max (over n regs, then 16-lane group)
    float rm[4];
#pragma unroll
    for (int r = 0; r < 4; ++r)
      rm[r] = fmaxf(fmaxf(s[0][r], s[1][r]), fmaxf(s[2][r], s[3][r]));
#pragma unroll
    for (int mk2 = 1; mk2 < 16; mk2 <<= 1) {
#pragma unroll
      for (int r = 0; r < 4; ++r) rm[r] = fmaxf(rm[r], __shfl_xor(rm[r], mk2, 64));
    }

    float sc[4];
#pragma unroll
    for (int r = 0; r < 4; ++r) {
      const float mn = fmaxf(mr[r], rm[r]);
      sc[r] = exp2f((mr[r] - mn) * 1.44269504f);
      mr[r] = mn;
    }

    // p = exp(s-m), store to swizzled Ps, row-sum
    float rs[4] = {0.f, 0.f, 0.f, 0.f};
#pragma unroll
    for (int n = 0; n < 4; ++n) {
#pragma unroll
      for (int r = 0; r < 4; ++r) {
        const float p = exp2f((s[n][r] - mr[r]) * 1.44269504f);
        rs[r] += p;
        const int row16 = g * 4 + r;
        const int byte = row16 * 128 + (((n * 16 + c15) * 2) ^ ((row16 & 7) << 4));
        Ps[wid][byte >> 1] = f2bf(p);
      }
    }
#pragma unroll
    for (int mk2 = 1; mk2 < 16; mk2 <<= 1) {
#pragma unroll
      for (int r = 0; r < 4; ++r) rs[r] += __shfl_xor(rs[r], mk2, 64);
    }
#pragma unroll
    for (int r = 0; r < 4; ++r) lr2[r] = lr2[r] * sc[r] + rs[r];

    // redistribute per-row scale to q-indexed lanes, rescale O
#pragma unroll
    for (int r = 0; r < 4; ++r)
      if (c15 == r) red[wid][g * 4 + r] = sc[r];
    __builtin_amdgcn_s_waitcnt(0);  // lgkm drain before cross-lane LDS read (same wave)
    const float scq = red[wid][c15];
#pragma unroll
    for (int mb = 0; mb < 4; ++mb) {
#pragma unroll
      for (int r = 0; r < 4; ++r) oacc[mb][r] *= scq;
    }

    // O^T += V^T P^T  (A = Vt frags, B = P row-major frags)
#pragma unroll
    for (int ks = 0; ks < 2; ++ks) {
      const bf16x8 pb = *(const bf16x8*)&Ps[wid][(c15 * 128 + (((ks * 4 + g) * 16) ^ ((c15 & 7) << 4))) >> 1];
#pragma unroll
      for (int mb = 0; mb < 4; ++mb) {
        const bf16x8 av = *(const bf16x8*)&Vs[cur][(ks * 4 + g) * 512 + (mb * 16 + c15) * 8];
        oacc[mb] = __builtin_amdgcn_mfma_f32_16x16x32_bf16(av, pb, oacc[mb], 0, 0, 0);
      }
    }
    cur ^= 1;
  }

  // final 1/l and write (B,N,H) bf16
#pragma unroll
  for (int r = 0; r < 4; ++r)
    if (c15 == r) red[wid][g * 4 + r] = lr2[r];
  __builtin_amdgcn_s_waitcnt(0);
  const float linv = 1.0f / red[wid][c15];
  unsigned short* aop = AO + (b * 1024 + q0 + wid * 16 + c15) * 768 + h * 64;
#pragma unroll
  for (int mb = 0; mb < 4; ++mb) {
    ushort4 w;
    w.x = f2bf(oacc[mb][0] * linv);
    w.y = f2bf(oacc[mb][1] * linv);
    w.z = f2bf(oacc[mb][2] * linv);
    w.w = f2bf(oacc[mb][3] * linv);
    *(ushort4*)&aop[mb * 16 + g * 4] = w;
  }
}

// ---------------- launch ----------------

extern "C" void kernel_launch(void* const* d_in, const int* in_sizes, int n_in,
                              void* d_out, int out_size, void* d_ws, size_t ws_size,
                              hipStream_t stream) {
  (void)in_sizes; (void)n_in; (void)out_size; (void)ws_size;
  const float* x = (const float*)d_in[0];
  const int* E = (const int*)d_in[1];          // integer inputs arrive as int32
  const int* Mm = (const int*)d_in[2];
  const float* bq = (const float*)d_in[4];
  const float* bk = (const float*)d_in[6];
  const float* bv = (const float*)d_in[8];
  const float* Wq = (const float*)d_in[3];
  const float* Wk = (const float*)d_in[5];
  const float* Wv = (const float*)d_in[7];
  const float* Wo = (const float*)d_in[9];
  const float* bo = (const float*)d_in[10];
  const float* emb = (const float*)d_in[11];
  float* out = (float*)d_out;

  char* w = (char*)d_ws;
  unsigned short* x16 = (unsigned short*)w;  // reused as AO after gemm<0>
  unsigned short* AO = x16;
  w += (size_t)8192 * 768 * 2;
  unsigned short* wtqkv = (unsigned short*)w; w += (size_t)2304 * 768 * 2;
  unsigned short* wot = (unsigned short*)w;   w += (size_t)768 * 768 * 2;
  unsigned short* Qb = (unsigned short*)w;    w += (size_t)8 * 12 * 1024 * 64 * 2;
  unsigned short* Kb = (unsigned short*)w;    w += (size_t)8 * 12 * 1024 * 64 * 2;
  unsigned short* Vt = (unsigned short*)w;    w += (size_t)8 * 12 * 64 * 1024 * 2;
  uint8_t* E8 = (uint8_t*)w;                  w += (size_t)8 * 1024 * 1024;

  conv_x_k<<<6144, 256, 0, stream>>>(x, x16);
  conv_E_k<<<4096, 256, 0, stream>>>(E, E8);
  transp_w_k<<<dim3(12, 12, 4), 256, 0, stream>>>(Wq, Wk, Wv, Wo, wtqkv, wot);
  gemm_bt<0><<<dim3(64, 18), 256, 0, stream>>>(x16, wtqkv, bq, bk, bv, Qb, Kb, Vt, nullptr);
  attn_fused<<<dim3(16, 12, 8), 256, 0, stream>>>(Qb, Kb, Vt, E8, Mm, emb, AO);
  gemm_bt<1><<<dim3(64, 6), 256, 0, stream>>>(AO, wot, bo, nullptr, nullptr,
                                              nullptr, nullptr, nullptr, out);
}

// Round 3
// 174.107 us; speedup vs baseline: 1.6752x; 1.6752x over previous
//
#include <hip/hip_runtime.h>
#include <stdint.h>

#define DEV __device__ __forceinline__

typedef __attribute__((ext_vector_type(8))) short bf16x8;
typedef __attribute__((ext_vector_type(4))) float f32x4;
typedef __attribute__((ext_vector_type(16))) float f32x16;

DEV unsigned short f2bf(float f) {
  union { float f; uint32_t u; } v; v.f = f;
  uint32_t r = v.u + 0x7fffu + ((v.u >> 16) & 1u);
  return (unsigned short)(r >> 16);
}

DEV void lds_load16(void* dst, const void* src) {
  __builtin_amdgcn_global_load_lds(
      (const __attribute__((address_space(1))) unsigned int*)src,
      (__attribute__((address_space(3))) unsigned int*)dst, 16, 0, 0);
}

// ---------------- prep kernels ----------------

__global__ void conv_x_k(const float* __restrict__ x, unsigned short* __restrict__ o) {
  const int i = blockIdx.x * 256 + threadIdx.x;  // 1572864 float4s
  const float4 v = ((const float4*)x)[i];
  ushort4 u;
  u.x = f2bf(v.x); u.y = f2bf(v.y); u.z = f2bf(v.z); u.w = f2bf(v.w);
  ((ushort4*)o)[i] = u;
}

// E (int32) -> lane-ordered masked-index records.
// E8L[b][qw(32)][kt(16)][lane(64)][8 dwords]: dword j=4a+c, byte rr:
//   k = 32a + 8c + 4h + rr (h = lane>>5), q = qw*32 + (lane&31)
// value = (M[q]&&M[k]) ? E[b][q][k] : 32
__global__ void conv_E_k(const int* __restrict__ E, const int* __restrict__ Mm,
                         uint8_t* __restrict__ E8L) {
  const int tid = blockIdx.x * 256 + threadIdx.x;  // 2097152
  const int k4 = tid & 255;
  const int q = (tid >> 8) & 1023;
  const int b = tid >> 18;
  const uint4 e = ((const uint4*)E)[tid];
  const int mq = Mm[b * 1024 + q];
  const int4 mk = *(const int4*)&Mm[b * 1024 + k4 * 4];
  uint32_t r;
  {
    const uint32_t b0 = (mq && mk.x) ? (e.x & 31u) : 32u;
    const uint32_t b1 = (mq && mk.y) ? (e.y & 31u) : 32u;
    const uint32_t b2 = (mq && mk.z) ? (e.z & 31u) : 32u;
    const uint32_t b3 = (mq && mk.w) ? (e.w & 31u) : 32u;
    r = b0 | (b1 << 8) | (b2 << 16) | (b3 << 24);
  }
  const int kt = k4 >> 4;
  const int k4t = k4 & 15;
  const int h = k4t & 1, c = (k4t >> 1) & 3, a = k4t >> 3;
  const int lane = (h << 5) | (q & 31);
  const int qw = q >> 5;
  const int j = a * 4 + c;
  const size_t rec = ((((size_t)b * 32 + qw) * 16 + kt) * 64 + lane) * 32 + j * 4;
  *(uint32_t*)(E8L + rec) = r;
}

// Wt[c][k] = W[k][c], bf16 pack. grid (12,12,4)
__global__ void transp_w_k(const float* __restrict__ Wq, const float* __restrict__ Wk,
                           const float* __restrict__ Wv, const float* __restrict__ Wo,
                           unsigned short* __restrict__ wtqkv, unsigned short* __restrict__ wot) {
  __shared__ float tile[64][65];
  const int z = blockIdx.z;
  const float* W = (z == 0) ? Wq : (z == 1) ? Wk : (z == 2) ? Wv : Wo;
  unsigned short* D = (z < 3) ? wtqkv + (size_t)z * 768 * 768 : wot;
  const int k0 = blockIdx.x * 64;
  const int c0 = blockIdx.y * 64;
  const int t = threadIdx.x;
#pragma unroll
  for (int i = 0; i < 4; ++i) {
    const int idx = i * 256 + t;
    const int r = idx >> 4;
    const int cq = (idx & 15) * 4;
    const float4 v = *(const float4*)&W[(k0 + r) * 768 + c0 + cq];
    tile[r][cq] = v.x; tile[r][cq + 1] = v.y; tile[r][cq + 2] = v.z; tile[r][cq + 3] = v.w;
  }
  __syncthreads();
#pragma unroll
  for (int i = 0; i < 4; ++i) {
    const int idx = i * 256 + t;
    const int c = idx >> 4;
    const int kq = (idx & 15) * 4;
    ushort4 u;
    u.x = f2bf(tile[kq][c]);     u.y = f2bf(tile[kq + 1][c]);
    u.z = f2bf(tile[kq + 2][c]); u.w = f2bf(tile[kq + 3][c]);
    *(ushort4*)&D[(c0 + c) * 768 + k0 + kq] = u;
  }
}

// ---------------- GEMM: C = A(M,768) @ Bt^T + bias ----------------
template <int MODE>
__global__ __launch_bounds__(256, 2)
void gemm_bt(const unsigned short* __restrict__ A, const unsigned short* __restrict__ Bt,
             const float* __restrict__ b0, const float* __restrict__ b1, const float* __restrict__ b2,
             unsigned short* __restrict__ Qb, unsigned short* __restrict__ Kb,
             unsigned short* __restrict__ Vt, float* __restrict__ Fo) {
  __shared__ __attribute__((aligned(16))) unsigned short lds[2][8192];
  const int t = threadIdx.x;
  const int lane = t & 63;
  const int wid = t >> 6;
  const int m0 = blockIdx.x * 128;
  const int n0 = blockIdx.y * 128;
  const int wm = (wid >> 1) * 64;
  const int wn = (wid & 1) * 64;
  const int srow = t & 127;
  const int sk8 = (t >> 7) * 8;

  const unsigned short* gA = A + (m0 + srow) * 768 + sk8;
  const unsigned short* gB = Bt + (n0 + srow) * 768 + sk8;

  const f32x4 Z4 = {0.f, 0.f, 0.f, 0.f};
  f32x4 acc[4][4];
#pragma unroll
  for (int m = 0; m < 4; ++m)
#pragma unroll
    for (int n = 0; n < 4; ++n) acc[m][n] = Z4;

  const int a_off = (lane >> 4) * 1024 + (wm + (lane & 15)) * 8;
  const int b_off = 4096 + (lane >> 4) * 1024 + (wn + (lane & 15)) * 8;

  auto stage = [&](int buf, int kt) {
    unsigned short* dA = &lds[buf][0] + wid * 512;
    unsigned short* dB = &lds[buf][4096] + wid * 512;
    const unsigned short* sA = gA + kt * 32;
    const unsigned short* sB = gB + kt * 32;
    lds_load16(dA, sA);
    lds_load16(dA + 2048, sA + 16);
    lds_load16(dB, sB);
    lds_load16(dB + 2048, sB + 16);
  };

  stage(0, 0);
  int cur = 0;
  for (int kt = 0; kt < 24; ++kt) {
    __syncthreads();
    if (kt + 1 < 24) stage(cur ^ 1, kt + 1);
    bf16x8 av[4], bvv[4];
#pragma unroll
    for (int m = 0; m < 4; ++m) av[m] = *(const bf16x8*)&lds[cur][a_off + m * 128];
#pragma unroll
    for (int n = 0; n < 4; ++n) bvv[n] = *(const bf16x8*)&lds[cur][b_off + n * 128];
#pragma unroll
    for (int m = 0; m < 4; ++m)
#pragma unroll
      for (int n = 0; n < 4; ++n)
        acc[m][n] = __builtin_amdgcn_mfma_f32_16x16x32_bf16(av[m], bvv[n], acc[m][n], 0, 0, 0);
    cur ^= 1;
  }

  const int g = lane >> 4;
  const int c15 = lane & 15;
  if (MODE == 1) {
#pragma unroll
    for (int n = 0; n < 4; ++n) {
      const int col = n0 + wn + n * 16 + c15;
      const float bval = b0[col];
#pragma unroll
      for (int m = 0; m < 4; ++m) {
        const int r0 = m0 + wm + m * 16 + g * 4;
#pragma unroll
        for (int r = 0; r < 4; ++r) Fo[(r0 + r) * 768 + col] = acc[m][n][r] + bval;
      }
    }
  } else {
    const int mat = blockIdx.y / 6;
    const float* bsel = (mat == 0) ? b0 : (mat == 1) ? b1 : b2;
    unsigned short* qk = (mat == 0) ? Qb : Kb;
#pragma unroll
    for (int n = 0; n < 4; ++n) {
      const int cw = (blockIdx.y % 6) * 128 + wn + n * 16 + c15;
      const int hh = cw >> 6, dd = cw & 63;
      const float bval = bsel[cw];
#pragma unroll
      for (int m = 0; m < 4; ++m) {
        const int r0 = m0 + wm + m * 16 + g * 4;
        const int bb = r0 >> 10;
        const int nn = r0 & 1023;
        if (mat < 2) {
          unsigned short* dst = qk + ((bb * 12 + hh) * 1024 + nn) * 64 + dd;
#pragma unroll
          for (int r = 0; r < 4; ++r) dst[r * 64] = f2bf(acc[m][n][r] + bval);
        } else {
          ushort4 w;
          w.x = f2bf(acc[m][n][0] + bval);
          w.y = f2bf(acc[m][n][1] + bval);
          w.z = f2bf(acc[m][n][2] + bval);
          w.w = f2bf(acc[m][n][3] + bval);
          *(ushort4*)&Vt[((bb * 12 + hh) * 64 + dd) * 1024 + nn] = w;
        }
      }
    }
  }
}

// ---------------- fused attention, swapped-QK^T 32x32 (m214 structure) ----------------
// 4 waves/block, each wave owns 32 q-rows. Lane = one q-row (P lane-local).
__global__ __launch_bounds__(256, 3)
void attn_fused(const unsigned short* __restrict__ Qb, const unsigned short* __restrict__ Kb,
                const unsigned short* __restrict__ Vt, const uint8_t* __restrict__ E8L,
                const float* __restrict__ emb, unsigned short* __restrict__ AO) {
  __shared__ __attribute__((aligned(16))) unsigned short Ks[2][4096];  // [krow64][d64] swz
  __shared__ __attribute__((aligned(16))) unsigned short Vs[2][4096];  // [d64][k64] swz
  __shared__ float ttab[33];
  __shared__ float red[4][32];

  const int t = threadIdx.x;
  const int lane = t & 63;
  const int wid = t >> 6;
  const int l31 = lane & 31;
  const int hl = lane >> 5;

  // XCD swizzle: 768 blocks, 96/XCD = one batch per XCD
  const int id = blockIdx.x;
  const int sw = (id & 7) * 96 + (id >> 3);
  const int b = sw / 96;
  const int rem = sw - b * 96;
  const int h = rem >> 3;
  const int qb = rem & 7;
  const int bh = b * 12 + h;
  const int qw = qb * 4 + wid;   // global 32-row warp index
  const int q0 = qw * 32;

  if (t < 33) ttab[t] = (t < 32) ? emb[t * 12 + h] * 1.44269504f : -1e30f;

  // Q fragments in registers: qf[dc] = Q[q0+l31][dc*16 + hl*8 .. +8]
  bf16x8 qf[4];
  {
    const unsigned short* qp = Qb + ((size_t)bh * 1024 + q0 + l31) * 64 + hl * 8;
#pragma unroll
    for (int dc = 0; dc < 4; ++dc) qf[dc] = *(const bf16x8*)(qp + dc * 16);
  }

  auto stageKV = [&](int buf, int kt) {
#pragma unroll
    for (int i = 0; i < 2; ++i) {
      const int c = i * 256 + t;
      const int row = c >> 3, c16 = c & 7;
      const int sc = (c16 ^ (row & 7)) * 8;
      lds_load16(&Ks[buf][i * 2048 + wid * 512],
                 Kb + ((size_t)bh * 1024 + kt * 64 + row) * 64 + sc);
      lds_load16(&Vs[buf][i * 2048 + wid * 512],
                 Vt + ((size_t)bh * 64 + row) * 1024 + kt * 64 + sc);
    }
  };

  const uint8_t* ebase = E8L + (((size_t)(b * 32 + qw)) * 16 * 64 + lane) * 32;

  stageKV(0, 0);
  uint4 e0 = *(const uint4*)(ebase);
  uint4 e1 = *(const uint4*)(ebase + 16);

  const f32x16 Z16 = {0.f};
  f32x16 oacc0 = Z16, oacc1 = Z16;
  float m = -3.0e38f, lsum = 0.f;
  int cur = 0;

  for (int kt = 0; kt < 16; ++kt) {
    __syncthreads();
    if (kt + 1 < 16) stageKV(cur ^ 1, kt + 1);
    uint4 en0, en1;
    if (kt + 1 < 16) {
      en0 = *(const uint4*)(ebase + (kt + 1) * 2048);
      en1 = *(const uint4*)(ebase + (kt + 1) * 2048 + 16);
    }

    // ---- S^T = K Q : lane = q (l31), rows = k ----
    f32x16 s0 = Z16, s1 = Z16;
#pragma unroll
    for (int dc = 0; dc < 4; ++dc) {
      const int gch = (dc * 2 + hl);
      const bf16x8 a0 = *(const bf16x8*)((const char*)Ks[cur] +
                         l31 * 128 + ((gch ^ (l31 & 7)) << 4));
      const bf16x8 a1 = *(const bf16x8*)((const char*)Ks[cur] +
                         (32 + l31) * 128 + ((gch ^ ((32 + l31) & 7)) << 4));
      s0 = __builtin_amdgcn_mfma_f32_32x32x16_bf16(a0, qf[dc], s0, 0, 0, 0);
      s1 = __builtin_amdgcn_mfma_f32_32x32x16_bf16(a1, qf[dc], s1, 0, 0, 0);
    }

    // ---- bias via table (mask folded: idx 32 -> -1e30, absorbed exactly) ----
    const uint32_t ed[8] = {e0.x, e0.y, e0.z, e0.w, e1.x, e1.y, e1.z, e1.w};
    float w0[16], w1[16];
#pragma unroll
    for (int r = 0; r < 16; ++r) {
      const uint32_t d0 = ed[r >> 2], d1 = ed[4 + (r >> 2)];
      const int sh = (r & 3) * 8;
      w0[r] = fmaf(s0[r], 0.18033688f, ttab[(d0 >> sh) & 0xffu]);
      w1[r] = fmaf(s1[r], 0.18033688f, ttab[(d1 >> sh) & 0xffu]);
    }

    // ---- row max (in-register + partner swap) ----
    float rm = fmaxf(w0[0], w1[0]);
#pragma unroll
    for (int r = 1; r < 16; ++r) rm = fmaxf(rm, fmaxf(w0[r], w1[r]));
    rm = fmaxf(rm, __shfl_xor(rm, 32, 64));

    // ---- defer-max update (THR = 8*log2e) ----
    if (__any(rm > m + 11.5415603f)) {
      const float mn = fmaxf(m, rm);
      const float scl = exp2f(m - mn);
      m = mn;
      lsum *= scl;
#pragma unroll
      for (int r = 0; r < 16; ++r) { oacc0[r] *= scl; oacc1[r] *= scl; }
    }

    // ---- p = exp2(w - m), sum ----
    float rs0 = 0.f, rs1 = 0.f, rs2 = 0.f, rs3 = 0.f;
#pragma unroll
    for (int r = 0; r < 16; ++r) {
      w0[r] = exp2f(w0[r] - m);
      w1[r] = exp2f(w1[r] - m);
    }
#pragma unroll
    for (int r = 0; r < 4; ++r) {
      rs0 += w0[r];  rs1 += w0[4 + r];
      rs2 += w0[8 + r]; rs3 += w0[12 + r];
      rs0 += w1[r];  rs1 += w1[4 + r];
      rs2 += w1[8 + r]; rs3 += w1[12 + r];
    }
    float rs = (rs0 + rs1) + (rs2 + rs3);
    rs += __shfl_xor(rs, 32, 64);
    lsum += rs;

    // ---- pack P to bf16 frags: 16 cvt_pk + 8 permlane32_swap ----
    uint32_t wd0[8], wd1[8];
#pragma unroll
    for (int j = 0; j < 8; ++j) {
      asm("v_cvt_pk_bf16_f32 %0, %1, %2" : "=v"(wd0[j]) : "v"(w0[2 * j]), "v"(w0[2 * j + 1]));
      asm("v_cvt_pk_bf16_f32 %0, %1, %2" : "=v"(wd1[j]) : "v"(w1[2 * j]), "v"(w1[2 * j + 1]));
    }
#pragma unroll
    for (int cc = 0; cc < 2; ++cc) {
      asm volatile("v_permlane32_swap_b32 %0, %1" : "+v"(wd0[4 * cc]), "+v"(wd0[4 * cc + 2]));
      asm volatile("v_permlane32_swap_b32 %0, %1" : "+v"(wd0[4 * cc + 1]), "+v"(wd0[4 * cc + 3]));
      asm volatile("v_permlane32_swap_b32 %0, %1" : "+v"(wd1[4 * cc]), "+v"(wd1[4 * cc + 2]));
      asm volatile("v_permlane32_swap_b32 %0, %1" : "+v"(wd1[4 * cc + 1]), "+v"(wd1[4 * cc + 3]));
    }

    // ---- O += P V : A = P frag (lane row = q), B = V^T frag ----
#pragma unroll
    for (int kb = 0; kb < 4; ++kb) {
      union { uint32_t u[4]; bf16x8 v; } fu;
      const uint32_t* wds = (kb < 2) ? wd0 : wd1;
      const int cc = kb & 1;
      fu.u[0] = wds[4 * cc];     fu.u[1] = wds[4 * cc + 1];
      fu.u[2] = wds[4 * cc + 2]; fu.u[3] = wds[4 * cc + 3];
      const int gch = kb * 2 + hl;
      const bf16x8 v0 = *(const bf16x8*)((const char*)Vs[cur] +
                         l31 * 128 + ((gch ^ (l31 & 7)) << 4));
      const bf16x8 v1 = *(const bf16x8*)((const char*)Vs[cur] +
                         (32 + l31) * 128 + ((gch ^ ((32 + l31) & 7)) << 4));
      oacc0 = __builtin_amdgcn_mfma_f32_32x32x16_bf16(fu.v, v0, oacc0, 0, 0, 0);
      oacc1 = __builtin_amdgcn_mfma_f32_32x32x16_bf16(fu.v, v1, oacc1, 0, 0, 0);
    }

    e0 = en0; e1 = en1;
    cur ^= 1;
  }

  // ---- epilogue: 1/l redistribution + store ----
  red[wid][l31] = 1.0f / lsum;
  __syncthreads();
  unsigned short* aob = AO + ((size_t)b * 1024 + q0) * 768 + h * 64;
#pragma unroll
  for (int j = 0; j < 4; ++j) {
    const f32x4 lv = *(const f32x4*)&red[wid][8 * j + 4 * hl];
#pragma unroll
    for (int rr = 0; rr < 4; ++rr) {
      const int rowq = rr + 8 * j + 4 * hl;
      const int reg = 4 * j + rr;
      aob[rowq * 768 + l31]      = f2bf(oacc0[reg] * lv[rr]);
      aob[rowq * 768 + 32 + l31] = f2bf(oacc1[reg] * lv[rr]);
    }
  }
}

// ---------------- launch ----------------

extern "C" void kernel_launch(void* const* d_in, const int* in_sizes, int n_in,
                              void* d_out, int out_size, void* d_ws, size_t ws_size,
                              hipStream_t stream) {
  (void)in_sizes; (void)n_in; (void)out_size; (void)ws_size;
  const float* x = (const float*)d_in[0];
  const int* E = (const int*)d_in[1];
  const int* Mm = (const int*)d_in[2];
  const float* Wq = (const float*)d_in[3];
  const float* bq = (const float*)d_in[4];
  const float* Wk = (const float*)d_in[5];
  const float* bk = (const float*)d_in[6];
  const float* Wv = (const float*)d_in[7];
  const float* bv = (const float*)d_in[8];
  const float* Wo = (const float*)d_in[9];
  const float* bo = (const float*)d_in[10];
  const float* emb = (const float*)d_in[11];
  float* out = (float*)d_out;

  char* w = (char*)d_ws;
  unsigned short* x16 = (unsigned short*)w;  // reused as AO after gemm<0>
  unsigned short* AO = x16;
  w += (size_t)8192 * 768 * 2;
  unsigned short* wtqkv = (unsigned short*)w; w += (size_t)2304 * 768 * 2;
  unsigned short* wot = (unsigned short*)w;   w += (size_t)768 * 768 * 2;
  unsigned short* Qb = (unsigned short*)w;    w += (size_t)8 * 12 * 1024 * 64 * 2;
  unsigned short* Kb = (unsigned short*)w;    w += (size_t)8 * 12 * 1024 * 64 * 2;
  unsigned short* Vt = (unsigned short*)w;    w += (size_t)8 * 12 * 64 * 1024 * 2;
  uint8_t* E8L = (uint8_t*)w;                 w += (size_t)8 * 1024 * 1024;

  conv_x_k<<<6144, 256, 0, stream>>>(x, x16);
  conv_E_k<<<8192, 256, 0, stream>>>(E, Mm, E8L);
  transp_w_k<<<dim3(12, 12, 4), 256, 0, stream>>>(Wq, Wk, Wv, Wo, wtqkv, wot);
  gemm_bt<0><<<dim3(64, 18), 256, 0, stream>>>(x16, wtqkv, bq, bk, bv, Qb, Kb, Vt, nullptr);
  attn_fused<<<768, 256, 0, stream>>>(Qb, Kb, Vt, E8L, emb, AO);
  gemm_bt<1><<<dim3(64, 6), 256, 0, stream>>>(AO, wot, bo, nullptr, nullptr,
                                              nullptr, nullptr, nullptr, out);
}